// Round 4
// baseline (172.410 us; speedup 1.0000x reference)
//
#include <hip/hip_runtime.h>
#include <hip/hip_bf16.h>

// Problem constants (B=32, N=256, K=20, channels 3->64->128->256, fc 256->128->40)
#define B_ 32
#define N_ 256
#define K_ 20
#define C1 64
#define C2 128
#define C3 256
#define F1 128
#define F2 40
#define NEG_INF (-3.402823466e38f)

// ---------------------------------------------------------------------------
// Kernel 1: blocks [0,2048): per-point top-20 (one wave per point, barrier-free
// selection loop). blocks [2048,2064): weight transpose+scale-fold prep:
//   w1f[oc][d]  = w1[oc][d]*s1[oc]
//   w2T[k][oc]  = w2[oc][k]*s2[oc]       (64 k  x 128 oc)
//   w3T[k][oc]  = w3[oc][k]*s3[oc]       (128 k x 256 oc)
//   fc1T[n][j]  = fc1w[j][n]             (256 n x 128 j)
// Transposed layouts make every GEMM inner-loop weight load a coalesced
// wave-wide b64/b128 stream; BN scale fold is exact ((sum w x)*s == sum (ws) x).
// ---------------------------------------------------------------------------
__global__ __launch_bounds__(256) void k_topk_prep(const float* __restrict__ x,
    const float* __restrict__ w1, const float* __restrict__ s1,
    const float* __restrict__ w2, const float* __restrict__ s2,
    const float* __restrict__ w3, const float* __restrict__ s3,
    const float* __restrict__ fc1w,
    int* __restrict__ idx, float* __restrict__ w1f, float* __restrict__ w2T,
    float* __restrict__ w3T, float* __restrict__ fc1T) {
    const int t = threadIdx.x;
    __shared__ float xs[N_ * 3];
    __shared__ float xxs[N_];

    if (blockIdx.x >= 2048) {
        const int g = (blockIdx.x - 2048) * 256 + t;   // 0..4095
        if (g < 192) w1f[g] = w1[g] * s1[g / 3];
        #pragma unroll
        for (int i = 0; i < 2; ++i) {                   // w2T: 8192 elems
            const int e = g + i * 4096;
            const int oc = e >> 6, k = e & 63;
            w2T[k * C2 + oc] = w2[e] * s2[oc];
        }
        #pragma unroll
        for (int i = 0; i < 8; ++i) {                   // w3T: 32768 elems
            const int e = g + i * 4096;
            const int oc = e >> 7, k = e & 127;
            w3T[k * C3 + oc] = w3[e] * s3[oc];
        }
        #pragma unroll
        for (int i = 0; i < 8; ++i) {                   // fc1T: 32768 elems
            const int e = g + i * 4096;
            const int j = e >> 8, n = e & 255;
            fc1T[n * F1 + j] = fc1w[e];
        }
        return;
    }

    const int lane = t & 63;
    const int wave = t >> 6;
    const int b    = blockIdx.x >> 6;
    const int n    = ((blockIdx.x & 63) << 2) | wave;
    const int bn   = (b << 8) | n;

    const float* xb = x + (size_t)b * N_ * 3;
    for (int e = t; e < N_ * 3; e += 256) xs[e] = xb[e];
    __syncthreads();
    {
        const float a0 = xs[t * 3 + 0], a1 = xs[t * 3 + 1], a2 = xs[t * 3 + 2];
        xxs[t] = a0 * a0 + a1 * a1 + a2 * a2;
    }
    __syncthreads();

    const float nx = xs[n * 3 + 0], ny = xs[n * 3 + 1], nz = xs[n * 3 + 2];
    const float xxn = xxs[n];

    unsigned long long k0, k1, k2, k3;
    {
        unsigned long long kk[4];
        #pragma unroll
        for (int i = 0; i < 4; ++i) {
            const int m = lane + (i << 6);
            const float cx = xs[m * 3 + 0], cy = xs[m * 3 + 1], cz = xs[m * 3 + 2];
            const float v = 2.0f * (nx * cx + ny * cy + nz * cz) - xxn - xxs[m];
            unsigned u = __float_as_uint(v);
            unsigned key32 = (u & 0x80000000u) ? ~u : (u | 0x80000000u);
            kk[i] = ((unsigned long long)key32 << 8) | (unsigned)(255 - m);
        }
        k0 = kk[0]; k1 = kk[1]; k2 = kk[2]; k3 = kk[3];
    }

    int mine = 0;
    #pragma unroll 1
    for (int it = 0; it < K_; ++it) {
        unsigned long long ra = (k0 > k1) ? k0 : k1;
        unsigned long long rb = (k2 > k3) ? k2 : k3;
        unsigned long long rk = (ra > rb) ? ra : rb;
        #pragma unroll
        for (int s = 1; s < 64; s <<= 1) {
            unsigned long long ok = __shfl_xor(rk, s, 64);
            if (ok > rk) rk = ok;
        }
        const int ri = 255 - (int)(rk & 0xFFull);
        if (lane == it) mine = ri;
        if (lane == (ri & 63)) {
            const int slot = ri >> 6;
            if      (slot == 0) k0 = 0ull;
            else if (slot == 1) k1 = 0ull;
            else if (slot == 2) k2 = 0ull;
            else                k3 = 0ull;
        }
    }
    if (lane < K_) idx[(size_t)bn * K_ + lane] = mine;
}

// ---------------------------------------------------------------------------
// Kernel 2: per-point MLP, 512 blocks x 128 threads, 16 points/block.
// All layers: lane owns an oc-chunk (coalesced wT loads), wave owns a pt-half
// (8 pts), activations read wave-uniform from LDS (broadcast, conflict-free).
// No k-splits -> no merges. Occupancy 2 blocks/CU.
// ---------------------------------------------------------------------------
__global__ __launch_bounds__(128) void k_mlp(const float* __restrict__ x,
    const float* __restrict__ w1f, const float* __restrict__ b1,
    const float* __restrict__ w2T, const float* __restrict__ b2,
    const float* __restrict__ w3T, const float* __restrict__ b3,
    float* __restrict__ P) {
    const int t    = threadIdx.x;
    const int lane = t & 63;
    const int wv   = t >> 6;
    const int p0   = wv * 8;            // wave's 8-point half
    const int pbase = blockIdx.x * 16;

    __shared__ float xs[16 * 3];
    __shared__ float y1[C1 * 16];       // [c1][p]
    __shared__ float y2[C2 * 16];       // [c2][p]

    if (t < 48) xs[t] = x[(size_t)pbase * 3 + t];
    __syncthreads();

    // ---- layer 1: 64 x 3; thread = (oc, pt-half) ----
    {
        const int oc = t & 63;
        const float wa = w1f[oc * 3 + 0], wb = w1f[oc * 3 + 1], wc = w1f[oc * 3 + 2];
        const float bb = b1[oc];
        float o[8];
        #pragma unroll
        for (int p = 0; p < 8; ++p) {
            const int pp = p0 + p;
            o[p] = fmaxf(wa * xs[pp * 3 + 0] + wb * xs[pp * 3 + 1] + wc * xs[pp * 3 + 2] + bb, 0.0f);
        }
        *(float4*)&y1[oc * 16 + p0]     = make_float4(o[0], o[1], o[2], o[3]);
        *(float4*)&y1[oc * 16 + p0 + 4] = make_float4(o[4], o[5], o[6], o[7]);
    }
    __syncthreads();

    // ---- layer 2: 128oc x 64k; lane owns oc {2l,2l+1}, full k ----
    {
        float acc[2][8] = {};
        #pragma unroll 4
        for (int k = 0; k < C1; ++k) {
            const float2 w = *(const float2*)&w2T[k * C2 + lane * 2];   // coalesced
            const float4 a0 = *(const float4*)&y1[k * 16 + p0];         // broadcast
            const float4 a1 = *(const float4*)&y1[k * 16 + p0 + 4];
            #pragma unroll
            for (int p = 0; p < 4; ++p) {
                acc[0][p]     += w.x * (&a0.x)[p];
                acc[0][p + 4] += w.x * (&a1.x)[p];
                acc[1][p]     += w.y * (&a0.x)[p];
                acc[1][p + 4] += w.y * (&a1.x)[p];
            }
        }
        #pragma unroll
        for (int o = 0; o < 2; ++o) {
            const int oc = lane * 2 + o;
            const float bb = b2[oc];
            float v[8];
            #pragma unroll
            for (int p = 0; p < 8; ++p) v[p] = fmaxf(acc[o][p] + bb, 0.0f);
            *(float4*)&y2[oc * 16 + p0]     = make_float4(v[0], v[1], v[2], v[3]);
            *(float4*)&y2[oc * 16 + p0 + 4] = make_float4(v[4], v[5], v[6], v[7]);
        }
    }
    __syncthreads();

    // ---- layer 3: 256oc x 128k; lane owns oc [4l,4l+4), full k ----
    {
        float acc[4][8] = {};
        #pragma unroll 4
        for (int k = 0; k < C2; ++k) {
            const float4 w = *(const float4*)&w3T[k * C3 + lane * 4];   // coalesced 1KB
            const float4 a0 = *(const float4*)&y2[k * 16 + p0];         // broadcast
            const float4 a1 = *(const float4*)&y2[k * 16 + p0 + 4];
            #pragma unroll
            for (int o = 0; o < 4; ++o) {
                const float wv_ = (&w.x)[o];
                #pragma unroll
                for (int p = 0; p < 4; ++p) {
                    acc[o][p]     += wv_ * (&a0.x)[p];
                    acc[o][p + 4] += wv_ * (&a1.x)[p];
                }
            }
        }
        const float4 bb = *(const float4*)&b3[lane * 4];
        #pragma unroll
        for (int p = 0; p < 8; ++p) {
            float4 v;
            #pragma unroll
            for (int o = 0; o < 4; ++o)
                (&v.x)[o] = fmaxf(acc[o][p] + (&bb.x)[o], 0.0f);
            *(float4*)&P[(size_t)(pbase + p0 + p) * C3 + lane * 4] = v;  // coalesced
        }
    }
}

// ---------------------------------------------------------------------------
// Kernel 3: gather-max over the 20 neighbors, one wave per (b,n) row.
// ---------------------------------------------------------------------------
__global__ __launch_bounds__(256) void k_gmax(const float* __restrict__ P,
                                              const int* __restrict__ idx,
                                              float* __restrict__ H) {
    const int t    = threadIdx.x;
    const int lane = t & 63;
    const int bn   = blockIdx.x * 4 + (t >> 6);
    const int b    = bn >> 8;

    const float* Pb = P + (size_t)b * N_ * C3;
    const int*   ib = idx + (size_t)bn * K_;

    float4 m = make_float4(NEG_INF, NEG_INF, NEG_INF, NEG_INF);
    #pragma unroll
    for (int j = 0; j < K_; ++j) {
        const int id = ib[j];
        const float4 p = ((const float4*)(Pb + (size_t)id * C3))[lane];
        m.x = fmaxf(m.x, p.x);
        m.y = fmaxf(m.y, p.y);
        m.z = fmaxf(m.z, p.z);
        m.w = fmaxf(m.w, p.w);
    }
    ((float4*)(H + (size_t)bn * C3))[lane] = m;
}

// ---------------------------------------------------------------------------
// Kernel 4: fused fc1(relu)+fc2. 1024 blocks (b, 8-ch tile) x 128 threads.
// fc1: lane owns j {2l,2l+1} (coalesced fc1T), wave owns 4-ch half, n full.
// fc2: 80 active threads, (m, ch-quad), weights staged in LDS (pad 129).
// ---------------------------------------------------------------------------
__global__ __launch_bounds__(128) void k_fc(const float* __restrict__ H,
                                            const float* __restrict__ fc1T,
                                            const float* __restrict__ fc1b,
                                            const float* __restrict__ fc2w,
                                            const float* __restrict__ fc2b,
                                            float* __restrict__ out) {
    const int b   = blockIdx.x >> 5;
    const int ch0 = (blockIdx.x & 31) * 8;
    const int t   = threadIdx.x;
    const int lane = t & 63;
    const int c0   = (t >> 6) * 4;      // wave's 4-ch half

    __shared__ float Ht[N_ * 8];        // [n][ci], 8 KB
    __shared__ float gl[8 * 132];       // [ci][j], padded stride 132
    __shared__ float w2l[F2 * 129];     // [m][j], padded (129 = 1 mod 32)

    const float* Hb = H + (size_t)b * N_ * C3;
    for (int e = t; e < N_ * 8; e += 128) {
        const int n = e >> 3, ci = e & 7;
        Ht[e] = Hb[(size_t)n * C3 + ch0 + ci];
    }
    for (int e = t; e < F2 * F1; e += 128)
        w2l[(e >> 7) * 129 + (e & 127)] = fc2w[e];
    __syncthreads();

    // ---- fc1 + relu ----
    {
        float acc[2][4] = {};
        #pragma unroll 4
        for (int n = 0; n < N_; ++n) {
            const float2 w = *(const float2*)&fc1T[n * F1 + lane * 2];  // coalesced
            const float4 a = *(const float4*)&Ht[n * 8 + c0];           // broadcast
            #pragma unroll
            for (int c = 0; c < 4; ++c) {
                acc[0][c] += w.x * (&a.x)[c];
                acc[1][c] += w.y * (&a.x)[c];
            }
        }
        const float bb0 = fc1b[lane * 2], bb1 = fc1b[lane * 2 + 1];
        #pragma unroll
        for (int c = 0; c < 4; ++c) {
            float2 v;
            v.x = fmaxf(acc[0][c] + bb0, 0.0f);
            v.y = fmaxf(acc[1][c] + bb1, 0.0f);
            *(float2*)&gl[(c0 + c) * 132 + lane * 2] = v;   // consecutive banks
        }
    }
    __syncthreads();

    // ---- fc2 ----
    if (t < 80) {
        const int m   = t % 40;
        const int ci0 = (t / 40) * 4;
        float a4[4] = {};
        for (int j = 0; j < F1; ++j) {
            const float w = w2l[m * 129 + j];
            #pragma unroll
            for (int c = 0; c < 4; ++c)
                a4[c] += w * gl[(ci0 + c) * 132 + j];
        }
        const float bm = fc2b[m];
        #pragma unroll
        for (int c = 0; c < 4; ++c)
            out[((size_t)(b * C3 + ch0 + ci0 + c)) * F2 + m] = a4[c] + bm;
    }
}

// ---------------------------------------------------------------------------
extern "C" void kernel_launch(void* const* d_in, const int* in_sizes, int n_in,
                              void* d_out, int out_size, void* d_ws, size_t ws_size,
                              hipStream_t stream) {
    const float* x    = (const float*)d_in[0];
    const float* w1   = (const float*)d_in[1];
    const float* s1   = (const float*)d_in[2];
    const float* t1   = (const float*)d_in[3];
    const float* w2   = (const float*)d_in[4];
    const float* s2   = (const float*)d_in[5];
    const float* t2   = (const float*)d_in[6];
    const float* w3   = (const float*)d_in[7];
    const float* s3   = (const float*)d_in[8];
    const float* t3   = (const float*)d_in[9];
    const float* fc1w = (const float*)d_in[10];
    const float* fc1b = (const float*)d_in[11];
    const float* fc2w = (const float*)d_in[12];
    const float* fc2b = (const float*)d_in[13];
    float* out = (float*)d_out;

    // Workspace layout (all fully overwritten every call):
    char* ws = (char*)d_ws;
    int*   idx  = (int*)ws;                                  // 655,360 B
    float* P    = (float*)(ws + (size_t)B_ * N_ * K_ * 4);   // 8 MB
    float* H    = P + (size_t)B_ * N_ * C3;                  // 8 MB
    float* w1f  = H + (size_t)B_ * N_ * C3;                  // 192 f
    float* w2T  = w1f + 256;                                 // 8192 f
    float* w3T  = w2T + C1 * C2;                             // 32768 f
    float* fc1T = w3T + C2 * C3;                             // 32768 f

    k_topk_prep<<<2048 + 16, 256, 0, stream>>>(x, w1, s1, w2, s2, w3, s3, fc1w,
                                               idx, w1f, w2T, w3T, fc1T);
    k_mlp <<<(B_ * N_) / 16, 128, 0, stream>>>(x, w1f, t1, w2T, t2, w3T, t3, P);
    k_gmax<<<(B_ * N_) / 4, 256, 0, stream>>>(P, idx, H);
    k_fc  <<<B_ * 32, 128, 0, stream>>>(H, fc1T, fc1b, fc2w, fc2b, out);
}

// Round 5
// 163.938 us; speedup vs baseline: 1.0517x; 1.0517x over previous
//
#include <hip/hip_runtime.h>
#include <hip/hip_bf16.h>

// Problem constants (B=32, N=256, K=20, channels 3->64->128->256, fc 256->128->40)
#define B_ 32
#define N_ 256
#define K_ 20
#define C1 64
#define C2 128
#define C3 256
#define F1 128
#define F2 40
#define NEG_INF (-3.402823466e38f)

// ---------------------------------------------------------------------------
// Kernel 1: blocks [0,2048): per-point top-20 (one wave per point, barrier-free
// selection loop). blocks [2048,2064): weight transpose+scale-fold prep:
//   w1f[oc][d]  = w1[oc][d]*s1[oc]
//   w2T[k][oc]  = w2[oc][k]*s2[oc]       (64 k  x 128 oc)
//   w3T[k][oc]  = w3[oc][k]*s3[oc]       (128 k x 256 oc)
//   fc1T[n][j]  = fc1w[j][n]             (256 n x 128 j)
// Transposed layouts make every GEMM inner-loop weight load a coalesced
// wave-wide stream; BN scale fold is exact ((sum w x)*s == sum (ws) x).
// ---------------------------------------------------------------------------
__global__ __launch_bounds__(256) void k_topk_prep(const float* __restrict__ x,
    const float* __restrict__ w1, const float* __restrict__ s1,
    const float* __restrict__ w2, const float* __restrict__ s2,
    const float* __restrict__ w3, const float* __restrict__ s3,
    const float* __restrict__ fc1w,
    int* __restrict__ idx, float* __restrict__ w1f, float* __restrict__ w2T,
    float* __restrict__ w3T, float* __restrict__ fc1T) {
    const int t = threadIdx.x;
    __shared__ float xs[N_ * 3];
    __shared__ float xxs[N_];

    if (blockIdx.x >= 2048) {
        const int g = (blockIdx.x - 2048) * 256 + t;   // 0..4095
        if (g < 192) w1f[g] = w1[g] * s1[g / 3];
        #pragma unroll
        for (int i = 0; i < 2; ++i) {                   // w2T: 8192 elems
            const int e = g + i * 4096;
            const int oc = e >> 6, k = e & 63;
            w2T[k * C2 + oc] = w2[e] * s2[oc];
        }
        #pragma unroll
        for (int i = 0; i < 8; ++i) {                   // w3T: 32768 elems
            const int e = g + i * 4096;
            const int oc = e >> 7, k = e & 127;
            w3T[k * C3 + oc] = w3[e] * s3[oc];
        }
        #pragma unroll
        for (int i = 0; i < 8; ++i) {                   // fc1T: 32768 elems
            const int e = g + i * 4096;
            const int j = e >> 8, n = e & 255;
            fc1T[n * F1 + j] = fc1w[e];
        }
        return;
    }

    const int lane = t & 63;
    const int wave = t >> 6;
    const int b    = blockIdx.x >> 6;
    const int n    = ((blockIdx.x & 63) << 2) | wave;
    const int bn   = (b << 8) | n;

    const float* xb = x + (size_t)b * N_ * 3;
    for (int e = t; e < N_ * 3; e += 256) xs[e] = xb[e];
    __syncthreads();
    {
        const float a0 = xs[t * 3 + 0], a1 = xs[t * 3 + 1], a2 = xs[t * 3 + 2];
        xxs[t] = a0 * a0 + a1 * a1 + a2 * a2;
    }
    __syncthreads();

    const float nx = xs[n * 3 + 0], ny = xs[n * 3 + 1], nz = xs[n * 3 + 2];
    const float xxn = xxs[n];

    unsigned long long k0, k1, k2, k3;
    {
        unsigned long long kk[4];
        #pragma unroll
        for (int i = 0; i < 4; ++i) {
            const int m = lane + (i << 6);
            const float cx = xs[m * 3 + 0], cy = xs[m * 3 + 1], cz = xs[m * 3 + 2];
            const float v = 2.0f * (nx * cx + ny * cy + nz * cz) - xxn - xxs[m];
            unsigned u = __float_as_uint(v);
            unsigned key32 = (u & 0x80000000u) ? ~u : (u | 0x80000000u);
            kk[i] = ((unsigned long long)key32 << 8) | (unsigned)(255 - m);
        }
        k0 = kk[0]; k1 = kk[1]; k2 = kk[2]; k3 = kk[3];
    }

    int mine = 0;
    #pragma unroll 1
    for (int it = 0; it < K_; ++it) {
        unsigned long long ra = (k0 > k1) ? k0 : k1;
        unsigned long long rb = (k2 > k3) ? k2 : k3;
        unsigned long long rk = (ra > rb) ? ra : rb;
        #pragma unroll
        for (int s = 1; s < 64; s <<= 1) {
            unsigned long long ok = __shfl_xor(rk, s, 64);
            if (ok > rk) rk = ok;
        }
        const int ri = 255 - (int)(rk & 0xFFull);
        if (lane == it) mine = ri;
        if (lane == (ri & 63)) {
            const int slot = ri >> 6;
            if      (slot == 0) k0 = 0ull;
            else if (slot == 1) k1 = 0ull;
            else if (slot == 2) k2 = 0ull;
            else                k3 = 0ull;
        }
    }
    if (lane < K_) idx[(size_t)bn * K_ + lane] = mine;
}

// ---------------------------------------------------------------------------
// Kernel 2: per-point MLP, 512 blocks x 128 threads, 16 points/block.
// All layers: lane owns an oc-chunk (coalesced wT loads), wave owns a pt-half
// (8 pts), activations read wave-uniform from LDS (broadcast, conflict-free).
// ---------------------------------------------------------------------------
__global__ __launch_bounds__(128) void k_mlp(const float* __restrict__ x,
    const float* __restrict__ w1f, const float* __restrict__ b1,
    const float* __restrict__ w2T, const float* __restrict__ b2,
    const float* __restrict__ w3T, const float* __restrict__ b3,
    float* __restrict__ P) {
    const int t    = threadIdx.x;
    const int lane = t & 63;
    const int wv   = t >> 6;
    const int p0   = wv * 8;            // wave's 8-point half
    const int pbase = blockIdx.x * 16;

    __shared__ float xs[16 * 3];
    __shared__ float y1[C1 * 16];       // [c1][p]
    __shared__ float y2[C2 * 16];       // [c2][p]

    if (t < 48) xs[t] = x[(size_t)pbase * 3 + t];
    __syncthreads();

    // ---- layer 1: 64 x 3; thread = (oc, pt-half) ----
    {
        const int oc = t & 63;
        const float wa = w1f[oc * 3 + 0], wb = w1f[oc * 3 + 1], wc = w1f[oc * 3 + 2];
        const float bb = b1[oc];
        float o[8];
        #pragma unroll
        for (int p = 0; p < 8; ++p) {
            const int pp = p0 + p;
            o[p] = fmaxf(wa * xs[pp * 3 + 0] + wb * xs[pp * 3 + 1] + wc * xs[pp * 3 + 2] + bb, 0.0f);
        }
        *(float4*)&y1[oc * 16 + p0]     = make_float4(o[0], o[1], o[2], o[3]);
        *(float4*)&y1[oc * 16 + p0 + 4] = make_float4(o[4], o[5], o[6], o[7]);
    }
    __syncthreads();

    // ---- layer 2: 128oc x 64k; lane owns oc {2l,2l+1}, full k ----
    {
        float acc[2][8] = {};
        #pragma unroll 4
        for (int k = 0; k < C1; ++k) {
            const float2 w = *(const float2*)&w2T[k * C2 + lane * 2];   // coalesced
            const float4 a0 = *(const float4*)&y1[k * 16 + p0];         // broadcast
            const float4 a1 = *(const float4*)&y1[k * 16 + p0 + 4];
            #pragma unroll
            for (int p = 0; p < 4; ++p) {
                acc[0][p]     += w.x * (&a0.x)[p];
                acc[0][p + 4] += w.x * (&a1.x)[p];
                acc[1][p]     += w.y * (&a0.x)[p];
                acc[1][p + 4] += w.y * (&a1.x)[p];
            }
        }
        #pragma unroll
        for (int o = 0; o < 2; ++o) {
            const int oc = lane * 2 + o;
            const float bb = b2[oc];
            float v[8];
            #pragma unroll
            for (int p = 0; p < 8; ++p) v[p] = fmaxf(acc[o][p] + bb, 0.0f);
            *(float4*)&y2[oc * 16 + p0]     = make_float4(v[0], v[1], v[2], v[3]);
            *(float4*)&y2[oc * 16 + p0 + 4] = make_float4(v[4], v[5], v[6], v[7]);
        }
    }
    __syncthreads();

    // ---- layer 3: 256oc x 128k; lane owns oc [4l,4l+4), full k ----
    {
        float acc[4][8] = {};
        #pragma unroll 4
        for (int k = 0; k < C2; ++k) {
            const float4 w = *(const float4*)&w3T[k * C3 + lane * 4];   // coalesced 1KB
            const float4 a0 = *(const float4*)&y2[k * 16 + p0];         // broadcast
            const float4 a1 = *(const float4*)&y2[k * 16 + p0 + 4];
            #pragma unroll
            for (int o = 0; o < 4; ++o) {
                const float wv_ = (&w.x)[o];
                #pragma unroll
                for (int p = 0; p < 4; ++p) {
                    acc[o][p]     += wv_ * (&a0.x)[p];
                    acc[o][p + 4] += wv_ * (&a1.x)[p];
                }
            }
        }
        const float4 bb = *(const float4*)&b3[lane * 4];
        #pragma unroll
        for (int p = 0; p < 8; ++p) {
            float4 v;
            #pragma unroll
            for (int o = 0; o < 4; ++o)
                (&v.x)[o] = fmaxf(acc[o][p] + (&bb.x)[o], 0.0f);
            *(float4*)&P[(size_t)(pbase + p0 + p) * C3 + lane * 4] = v;  // coalesced
        }
    }
}

// ---------------------------------------------------------------------------
// Kernel 3: FUSED gather-max + fc1(relu) + fc2.
// 512 blocks = (b, 16-ch tile) x 256 threads.
// Stage A: lane = (n-quarter, ch-quad) -> aligned 64B-segment gathers from P,
//          max over the 20 neighbors straight into LDS Ht[n][16].
// Stage B: fc1 over n (lane owns j-pair, wave owns ch-quad; coalesced fc1T).
// Stage C: fc2 from LDS (w2l padded 129, gl padded 132).
// ---------------------------------------------------------------------------
__global__ __launch_bounds__(256) void k_gfc(const float* __restrict__ P,
                                             const int* __restrict__ idx,
                                             const float* __restrict__ fc1T,
                                             const float* __restrict__ fc1b,
                                             const float* __restrict__ fc2w,
                                             const float* __restrict__ fc2b,
                                             float* __restrict__ out) {
    const int b    = blockIdx.x >> 4;
    const int ch0  = (blockIdx.x & 15) * 16;
    const int t    = threadIdx.x;
    const int lane = t & 63;

    __shared__ float Ht[N_ * 16];       // [n][ci], 16 KB
    __shared__ float gl[16 * 132];      // [ci][j], padded stride 132
    __shared__ float w2l[F2 * 129];     // [m][j], padded (129 = 1 mod 32)

    // stage fc2 weights (independent of stage A; same barrier covers both)
    for (int e = t; e < F2 * F1; e += 256)
        w2l[(e >> 7) * 129 + (e & 127)] = fc2w[e];

    // ---- stage A: gather-max into Ht ----
    {
        const int q  = t & 3;           // ch-quad
        const int nl = t >> 2;          // n within quarter-pass
        const float* Pq = P + (size_t)b * N_ * C3 + ch0 + q * 4;
        #pragma unroll
        for (int r = 0; r < 4; ++r) {
            const int n = r * 64 + nl;
            const int* ib = idx + ((size_t)((b << 8) | n)) * K_;
            float4 m = make_float4(NEG_INF, NEG_INF, NEG_INF, NEG_INF);
            #pragma unroll
            for (int j = 0; j < K_; ++j) {
                const int id = ib[j];
                const float4 p = *(const float4*)(Pq + (size_t)id * C3);
                m.x = fmaxf(m.x, p.x);
                m.y = fmaxf(m.y, p.y);
                m.z = fmaxf(m.z, p.z);
                m.w = fmaxf(m.w, p.w);
            }
            *(float4*)&Ht[n * 16 + q * 4] = m;   // byte 16*t pattern: conflict-free
        }
    }
    __syncthreads();

    // ---- stage B: fc1 + relu -> gl[ci][j] ----
    {
        const int c0 = (t >> 6) * 4;    // wave's ch-quad
        float acc[2][4] = {};
        #pragma unroll 4
        for (int n = 0; n < N_; ++n) {
            const float2 w = *(const float2*)&fc1T[n * F1 + lane * 2];  // coalesced
            const float4 a = *(const float4*)&Ht[n * 16 + c0];          // broadcast
            #pragma unroll
            for (int c = 0; c < 4; ++c) {
                acc[0][c] += w.x * (&a.x)[c];
                acc[1][c] += w.y * (&a.x)[c];
            }
        }
        const float bb0 = fc1b[lane * 2], bb1 = fc1b[lane * 2 + 1];
        #pragma unroll
        for (int c = 0; c < 4; ++c) {
            float2 v;
            v.x = fmaxf(acc[0][c] + bb0, 0.0f);
            v.y = fmaxf(acc[1][c] + bb1, 0.0f);
            *(float2*)&gl[(c0 + c) * 132 + lane * 2] = v;
        }
    }
    __syncthreads();

    // ---- stage C: fc2 -> out ----
    for (int o = t; o < 16 * F2; o += 256) {
        const int ci = o / F2;
        const int m  = o % F2;
        float acc = fc2b[m];
        const float* wr = w2l + m * 129;
        const float* gr = gl + ci * 132;
        #pragma unroll 4
        for (int j = 0; j < F1; ++j)
            acc += wr[j] * gr[j];
        out[((size_t)(b * C3 + ch0 + ci)) * F2 + m] = acc;
    }
}

// ---------------------------------------------------------------------------
extern "C" void kernel_launch(void* const* d_in, const int* in_sizes, int n_in,
                              void* d_out, int out_size, void* d_ws, size_t ws_size,
                              hipStream_t stream) {
    const float* x    = (const float*)d_in[0];
    const float* w1   = (const float*)d_in[1];
    const float* s1   = (const float*)d_in[2];
    const float* t1   = (const float*)d_in[3];
    const float* w2   = (const float*)d_in[4];
    const float* s2   = (const float*)d_in[5];
    const float* t2   = (const float*)d_in[6];
    const float* w3   = (const float*)d_in[7];
    const float* s3   = (const float*)d_in[8];
    const float* t3   = (const float*)d_in[9];
    const float* fc1w = (const float*)d_in[10];
    const float* fc1b = (const float*)d_in[11];
    const float* fc2w = (const float*)d_in[12];
    const float* fc2b = (const float*)d_in[13];
    float* out = (float*)d_out;

    // Workspace layout (all fully overwritten every call):
    char* ws = (char*)d_ws;
    int*   idx  = (int*)ws;                                  // 655,360 B
    float* P    = (float*)(ws + (size_t)B_ * N_ * K_ * 4);   // 8 MB
    float* w1f  = P + (size_t)B_ * N_ * C3;                  // 192 f
    float* w2T  = w1f + 256;                                 // 8192 f
    float* w3T  = w2T + C1 * C2;                             // 32768 f
    float* fc1T = w3T + C2 * C3;                             // 32768 f

    k_topk_prep<<<2048 + 16, 256, 0, stream>>>(x, w1, s1, w2, s2, w3, s3, fc1w,
                                               idx, w1f, w2T, w3T, fc1T);
    k_mlp<<<(B_ * N_) / 16, 128, 0, stream>>>(x, w1f, t1, w2T, t2, w3T, t3, P);
    k_gfc<<<B_ * 16, 256, 0, stream>>>(P, idx, fc1T, fc1b, fc2w, fc2b, out);
}